// Round 1
// baseline (254.891 us; speedup 1.0000x reference)
//
#include <hip/hip_runtime.h>

#define NB 64
#define NC 256
#define NH 32
#define NW 32
#define NF (NC * NH * NW)   // 262144 per batch
#define NPAIR (NF / 2)      // 131072 complex pairs per batch

// ---------------------------------------------------------------------------
// Threefry-2x32 (JAX), 20 rounds. Bit-exact integer cipher.
// ---------------------------------------------------------------------------
struct U2 { unsigned a, b; };

__host__ __device__ constexpr unsigned rotl32(unsigned x, int d) {
  return (x << d) | (x >> (32 - d));
}

__host__ __device__ constexpr U2 tf2x32(unsigned k0, unsigned k1,
                                        unsigned x0, unsigned x1) {
  const unsigned ks0 = k0, ks1 = k1, ks2 = k0 ^ k1 ^ 0x1BD11BDAu;
  x0 += ks0; x1 += ks1;
  x0 += x1; x1 = rotl32(x1, 13); x1 ^= x0;
  x0 += x1; x1 = rotl32(x1, 15); x1 ^= x0;
  x0 += x1; x1 = rotl32(x1, 26); x1 ^= x0;
  x0 += x1; x1 = rotl32(x1, 6);  x1 ^= x0;
  x0 += ks1; x1 += ks2 + 1u;
  x0 += x1; x1 = rotl32(x1, 17); x1 ^= x0;
  x0 += x1; x1 = rotl32(x1, 29); x1 ^= x0;
  x0 += x1; x1 = rotl32(x1, 16); x1 ^= x0;
  x0 += x1; x1 = rotl32(x1, 24); x1 ^= x0;
  x0 += ks2; x1 += ks0 + 2u;
  x0 += x1; x1 = rotl32(x1, 13); x1 ^= x0;
  x0 += x1; x1 = rotl32(x1, 15); x1 ^= x0;
  x0 += x1; x1 = rotl32(x1, 26); x1 ^= x0;
  x0 += x1; x1 = rotl32(x1, 6);  x1 ^= x0;
  x0 += ks0; x1 += ks1 + 3u;
  x0 += x1; x1 = rotl32(x1, 17); x1 ^= x0;
  x0 += x1; x1 = rotl32(x1, 29); x1 ^= x0;
  x0 += x1; x1 = rotl32(x1, 16); x1 ^= x0;
  x0 += x1; x1 = rotl32(x1, 24); x1 ^= x0;
  x0 += ks1; x1 += ks2 + 4u;
  x0 += x1; x1 = rotl32(x1, 13); x1 ^= x0;
  x0 += x1; x1 = rotl32(x1, 15); x1 ^= x0;
  x0 += x1; x1 = rotl32(x1, 26); x1 ^= x0;
  x0 += x1; x1 = rotl32(x1, 6);  x1 ^= x0;
  x0 += ks2; x1 += ks0 + 5u;
  return U2{x0, x1};
}

// ---------------------------------------------------------------------------
// FORK1 = partitionable threefry (modern JAX default): element m of a
// 32-bit random_bits array = word0 ^ word1 of block (hi=0, lo=m).
// split(key, n): key i = both words of block (0, i).
// (If bench shows absmax ~700: switch to "original" halved-iota stream.)
// ---------------------------------------------------------------------------
__device__ inline unsigned rb32(unsigned k0, unsigned k1, unsigned m) {
  U2 r = tf2x32(k0, k1, 0u, m);
  return r.a ^ r.b;
}

// nk = split(key(42), 5); key(42) = (0, 42)
constexpr U2 NK0 = tf2x32(0u, 42u, 0u, 0u);
constexpr U2 NK1 = tf2x32(0u, 42u, 0u, 1u);
constexpr U2 NK2 = tf2x32(0u, 42u, 0u, 2u);
constexpr U2 NK3 = tf2x32(0u, 42u, 0u, 3u);
constexpr U2 NK4 = tf2x32(0u, 42u, 0u, 4u);
// kk = split(nk[4], 2)
constexpr U2 KK0 = tf2x32(NK4.a, NK4.b, 0u, 0u);
constexpr U2 KK1 = tf2x32(NK4.a, NK4.b, 0u, 1u);

// ---------------------------------------------------------------------------
// XLA ErfInv32 (Giles), with -log1p(-x*x). Matches XLA CPU/GPU expansion.
// ---------------------------------------------------------------------------
__device__ inline float erfinv_xla(float x) {
  float w = -log1pf(-x * x);
  float p;
  if (w < 5.0f) {
    w = w - 2.5f;
    p = 2.81022636e-08f;
    p = fmaf(p, w, 3.43273939e-07f);
    p = fmaf(p, w, -3.5233877e-06f);
    p = fmaf(p, w, -4.39150654e-06f);
    p = fmaf(p, w, 0.00021858087f);
    p = fmaf(p, w, -0.00125372503f);
    p = fmaf(p, w, -0.00417768164f);
    p = fmaf(p, w, 0.246640727f);
    p = fmaf(p, w, 1.50140941f);
  } else {
    w = sqrtf(w) - 3.0f;
    p = -0.000200214257f;
    p = fmaf(p, w, 0.000100950558f);
    p = fmaf(p, w, 0.00134934322f);
    p = fmaf(p, w, -0.00367342844f);
    p = fmaf(p, w, 0.00573950773f);
    p = fmaf(p, w, -0.0076224613f);
    p = fmaf(p, w, 0.00943887047f);
    p = fmaf(p, w, 1.00167406f);
    p = fmaf(p, w, 2.83297682f);
  }
  return p * x;
}

// jax.random.normal: bits -> uniform[lo,1) -> sqrt(2)*erfinv
// lo = nextafter(-1,0) = 0xBF7FFFFF; (maxval-minval) rounds to exactly 2.0f.
__device__ inline float normal_from_bits(unsigned bits) {
  const float lo = __uint_as_float(0xBF7FFFFFu);
  float u = __uint_as_float((bits >> 9) | 0x3F800000u) - 1.0f;  // [0,1)
  float v = fmaf(u, 2.0f, lo);   // mul by 2 exact, so fma == mul+add
  v = fmaxf(v, lo);
  return 1.41421356f * erfinv_xla(v);
}

// ---------------------------------------------------------------------------
// Kernel 1: sem[b,c] = mean over H*W. One wave per (b,c) row.
// ---------------------------------------------------------------------------
__global__ __launch_bounds__(256) void sem_kernel(const float* __restrict__ x,
                                                  float* __restrict__ sem) {
  int row = (blockIdx.x * 256 + threadIdx.x) >> 6;  // (b,c) row, 16384 total
  int lane = threadIdx.x & 63;
  const float* rp = x + (size_t)row * 1024;
  float acc = 0.0f;
#pragma unroll
  for (int i = 0; i < 4; ++i) {
    float4 v = *(const float4*)(rp + i * 256 + lane * 4);
    acc += v.x + v.y + v.z + v.w;
  }
#pragma unroll
  for (int off = 32; off > 0; off >>= 1) acc += __shfl_down(acc, off, 64);
  if (lane == 0) sem[row] = acc * (1.0f / 1024.0f);
}

// ---------------------------------------------------------------------------
// Kernel 2: per-batch head -> s[b,c] = weights * topk-mask
// ---------------------------------------------------------------------------
__global__ __launch_bounds__(256) void head_kernel(
    const float* __restrict__ sem_g, const float* __restrict__ channel_embed,
    const float* __restrict__ snr_w1, const float* __restrict__ snr_b1,
    const float* __restrict__ snr_w2, const float* __restrict__ snr_b2,
    const float* __restrict__ base_w1, const float* __restrict__ base_w2,
    const float* __restrict__ sem_proj, const float* __restrict__ cond_proj,
    const float* __restrict__ out_proj, const float* __restrict__ r_w1,
    const float* __restrict__ r_b1, const float* __restrict__ r_w2,
    const float* __restrict__ r_b2, const float* __restrict__ r_w3,
    const float* __restrict__ r_b3, float* __restrict__ s_out) {
  __shared__ float sem_s[256];
  __shared__ float sv1_s[16];
  __shared__ float cond_s[32];
  __shared__ float hid_s[16], g1_s[16];
  __shared__ float r1_s[64], r2_s[64];
  __shared__ float w_s[256];
  __shared__ int k_s;
  const int b = blockIdx.x, t = threadIdx.x;

  sem_s[t] = sem_g[b * 256 + t];
  if (t < 16) {
    const float s_in = (float)(10.0 / 28.0);  // SNR_DB / 28.0 as f32
    sv1_s[t] = fmaxf(0.0f, s_in * snr_w1[t] + snr_b1[t]);
  }
  __syncthreads();
  if (t < 16) {
    float a = snr_b2[t];
    for (int f = 0; f < 16; ++f) a += sv1_s[f] * snr_w2[t * 16 + f];
    cond_s[16 + t] = fmaxf(0.0f, a);
    cond_s[t] = channel_embed[2 * 16 + t];  // CH_IDX=2
  }
  __syncthreads();
  if (t < 16) {
    float a1 = 0.0f, a2 = 0.0f;
    for (int c = 0; c < 256; ++c) {
      float sc = sem_s[c];
      a1 += sc * base_w1[t * 256 + c];
      a2 += sc * sem_proj[t * 256 + c];
    }
    for (int j = 0; j < 32; ++j) a2 += cond_s[j] * cond_proj[t * 32 + j];
    hid_s[t] = fmaxf(0.0f, a1);
    g1_s[t] = fmaxf(0.0f, a2);
  } else if (t < 80) {
    int i = t - 16;
    float a = r_b1[i];
    for (int c = 0; c < 256; ++c) a += sem_s[c] * r_w1[i * 288 + c];
    for (int j = 0; j < 32; ++j) a += cond_s[j] * r_w1[i * 288 + 256 + j];
    r1_s[i] = fmaxf(0.0f, a);
  }
  __syncthreads();
  if (t < 64) {
    float a = r_b2[t];
    for (int j = 0; j < 64; ++j) a += r1_s[j] * r_w2[t * 64 + j];
    r2_s[t] = fmaxf(0.0f, a);
  }
  {
    float a1 = 0.0f, a2 = 0.0f;
    for (int i = 0; i < 16; ++i) {
      a1 += hid_s[i] * base_w2[t * 16 + i];
      a2 += g1_s[i] * out_proj[t * 16 + i];
    }
    float base = 1.0f / (1.0f + expf(-a1));
    float gate = 1.0f / (1.0f + expf(-a2));
    w_s[t] = base * gate;
  }
  __syncthreads();
  if (t == 0) {
    float a = r_b3[0];
    for (int j = 0; j < 64; ++j) a += r2_s[j] * r_w3[j];
    float raw = 1.0f / (1.0f + expf(-a));
    float dyn = 0.3f + 0.7f * raw;
    float cr = 0.15f + 0.7f * dyn;
    cr = fminf(fmaxf(cr, 0.3f), 1.0f);
    int k = (int)rintf(cr * 256.0f);  // round-half-even like jnp.round
    k_s = min(max(k, 1), 256);
  }
  __syncthreads();
  // stable descending rank (ties -> lower index first), matches argsort-stable
  {
    float wc = w_s[t];
    int cnt = 0;
    for (int j = 0; j < 256; ++j) {
      float wj = w_s[j];
      cnt += (wj > wc) || (wj == wc && j < t);
    }
    s_out[b * 256 + t] = (cnt < k_s) ? wc : 0.0f;
    // note: when masked, weights*mask == 0 exactly (matches ref)
    if (cnt < k_s) s_out[b * 256 + t] = wc;  // keep w
  }
}

// ---------------------------------------------------------------------------
// Kernel 3: channel sim + noise. One thread per complex pair (b, p).
// ---------------------------------------------------------------------------
__global__ __launch_bounds__(256) void sim_kernel(const float* __restrict__ x,
                                                  const float* __restrict__ s,
                                                  float* __restrict__ out) {
  __shared__ float std2_s[16];
  const unsigned t = blockIdx.x * 256u + threadIdx.x;  // 0 .. 64*131072-1
  const unsigned p = t & (NPAIR - 1u);
  const unsigned b = t >> 17;
  const unsigned q0 = 2u * p;          // flat offset within (C,H,W)
  const unsigned c = q0 >> 10;
  const unsigned h = (q0 >> 5) & 31u;

  // snr_map (randint span 29): shared by the 16 threads of one (b,c,h) row.
  // FORK2: trailing-2 layout -> higher=block(2j), lower=block(2j+1).
  if (threadIdx.x < 16) {
    unsigned pg = (blockIdx.x * 256u + threadIdx.x * 16u) & (NPAIR - 1u);
    unsigned bg = (blockIdx.x * 256u + threadIdx.x * 16u) >> 17;
    unsigned qg = 2u * pg;
    unsigned jg = bg * 8192u + (qg >> 10) * 32u + ((qg >> 5) & 31u);
    unsigned hb = rb32(KK0.a, KK0.b, 2u * jg);
    unsigned lb = rb32(KK0.a, KK0.b, 2u * jg + 1u);
    unsigned snr = ((hb % 29u) * 16u + (lb % 29u)) % 29u;  // mult = 2^32 % 29 = 16
    float e = (float)snr / 10.0f;
    std2_s[threadIdx.x] = sqrtf(2.0f / powf(10.0f, e));
  }
  __syncthreads();

  const size_t base = (size_t)b * NF + q0;
  const float2 xv = *(const float2*)(x + base);
  const float sc = s[b * 256u + c];
  const float xr = xv.x * sc, xi = xv.y * sc;

  const unsigned m = b * (unsigned)NPAIR + p;  // flat idx in (64, 131072)
  const float hr = normal_from_bits(rb32(NK0.a, NK0.b, m));
  const float hi_ = normal_from_bits(rb32(NK1.a, NK1.b, m));
  const float STD = sqrtf(0.2f);  // sqrt(POWER / 10^(SNR/10)) in f32
  const float nr = STD * normal_from_bits(rb32(NK2.a, NK2.b, m));
  const float ni = STD * normal_from_bits(rb32(NK3.a, NK3.b, m));

  const unsigned q = b * (unsigned)NF + q0;  // flat idx in (64, 262144)
  const float n20 = normal_from_bits(rb32(KK1.a, KK1.b, q));
  const float n21 = normal_from_bits(rb32(KK1.a, KK1.b, q + 1u));

  // fading, computed with the reference's exact expression shape
  const float yr = hr * xr - hi_ * xi + nr;
  const float yi = hr * xi + hi_ * xr + ni;
  const float den = hr * hr + hi_ * hi_;
  const float outr = (yr * hr + yi * hi_) / den;
  const float outi = (yi * hr - yr * hi_) / den;

  const float std2 = std2_s[threadIdx.x >> 4];
  float2 o;
  o.x = outr + std2 * n20;
  o.y = outi + std2 * n21;
  *(float2*)(out + base) = o;
}

// ---------------------------------------------------------------------------
extern "C" void kernel_launch(void* const* d_in, const int* in_sizes, int n_in,
                              void* d_out, int out_size, void* d_ws,
                              size_t ws_size, hipStream_t stream) {
  const float* x = (const float*)d_in[0];
  const float* channel_embed = (const float*)d_in[1];
  const float* snr_w1 = (const float*)d_in[2];
  const float* snr_b1 = (const float*)d_in[3];
  const float* snr_w2 = (const float*)d_in[4];
  const float* snr_b2 = (const float*)d_in[5];
  const float* base_w1 = (const float*)d_in[6];
  const float* base_w2 = (const float*)d_in[7];
  const float* sem_proj = (const float*)d_in[8];
  const float* cond_proj = (const float*)d_in[9];
  const float* out_proj = (const float*)d_in[10];
  const float* r_w1 = (const float*)d_in[11];
  const float* r_b1 = (const float*)d_in[12];
  const float* r_w2 = (const float*)d_in[13];
  const float* r_b2 = (const float*)d_in[14];
  const float* r_w3 = (const float*)d_in[15];
  const float* r_b3 = (const float*)d_in[16];

  float* sem = (float*)d_ws;              // 16384 floats
  float* s = sem + NB * NC;               // 16384 floats

  sem_kernel<<<NB * NC / 4, 256, 0, stream>>>(x, sem);
  head_kernel<<<NB, 256, 0, stream>>>(sem, channel_embed, snr_w1, snr_b1,
                                      snr_w2, snr_b2, base_w1, base_w2,
                                      sem_proj, cond_proj, out_proj, r_w1,
                                      r_b1, r_w2, r_b2, r_w3, r_b3, s);
  sim_kernel<<<NB * NPAIR / 256, 256, 0, stream>>>(x, s, (float*)d_out);
}

// Round 2
// 138.581 us; speedup vs baseline: 1.8393x; 1.8393x over previous
//
#include <hip/hip_runtime.h>

#define NB 64
#define NC 256
#define NF 262144          // C*H*W per batch
#define NPAIR 131072       // complex pairs per batch
#define NROWS 524288       // B*C*H  (snr_map rows)

// ---------------------------------------------------------------------------
// Threefry-2x32 (JAX), 20 rounds.
// ---------------------------------------------------------------------------
struct U2 { unsigned a, b; };

__host__ __device__ constexpr unsigned rotl32(unsigned x, int d) {
  return (x << d) | (x >> (32 - d));
}

__host__ __device__ constexpr U2 tf2x32(unsigned k0, unsigned k1,
                                        unsigned x0, unsigned x1) {
  const unsigned ks0 = k0, ks1 = k1, ks2 = k0 ^ k1 ^ 0x1BD11BDAu;
  x0 += ks0; x1 += ks1;
  x0 += x1; x1 = rotl32(x1, 13); x1 ^= x0;
  x0 += x1; x1 = rotl32(x1, 15); x1 ^= x0;
  x0 += x1; x1 = rotl32(x1, 26); x1 ^= x0;
  x0 += x1; x1 = rotl32(x1, 6);  x1 ^= x0;
  x0 += ks1; x1 += ks2 + 1u;
  x0 += x1; x1 = rotl32(x1, 17); x1 ^= x0;
  x0 += x1; x1 = rotl32(x1, 29); x1 ^= x0;
  x0 += x1; x1 = rotl32(x1, 16); x1 ^= x0;
  x0 += x1; x1 = rotl32(x1, 24); x1 ^= x0;
  x0 += ks2; x1 += ks0 + 2u;
  x0 += x1; x1 = rotl32(x1, 13); x1 ^= x0;
  x0 += x1; x1 = rotl32(x1, 15); x1 ^= x0;
  x0 += x1; x1 = rotl32(x1, 26); x1 ^= x0;
  x0 += x1; x1 = rotl32(x1, 6);  x1 ^= x0;
  x0 += ks0; x1 += ks1 + 3u;
  x0 += x1; x1 = rotl32(x1, 17); x1 ^= x0;
  x0 += x1; x1 = rotl32(x1, 29); x1 ^= x0;
  x0 += x1; x1 = rotl32(x1, 16); x1 ^= x0;
  x0 += x1; x1 = rotl32(x1, 24); x1 ^= x0;
  x0 += ks1; x1 += ks2 + 4u;
  x0 += x1; x1 = rotl32(x1, 13); x1 ^= x0;
  x0 += x1; x1 = rotl32(x1, 15); x1 ^= x0;
  x0 += x1; x1 = rotl32(x1, 26); x1 ^= x0;
  x0 += x1; x1 = rotl32(x1, 6);  x1 ^= x0;
  x0 += ks2; x1 += ks0 + 5u;
  return U2{x0, x1};
}

// nk = split(key(42), 5); key(42) = (0, 42)
constexpr U2 NK0 = tf2x32(0u, 42u, 0u, 0u);
constexpr U2 NK1 = tf2x32(0u, 42u, 0u, 1u);
constexpr U2 NK2 = tf2x32(0u, 42u, 0u, 2u);
constexpr U2 NK3 = tf2x32(0u, 42u, 0u, 3u);
constexpr U2 NK4 = tf2x32(0u, 42u, 0u, 4u);
// kk = split(nk[4], 2)
constexpr U2 KK0 = tf2x32(NK4.a, NK4.b, 0u, 0u);
constexpr U2 KK1 = tf2x32(NK4.a, NK4.b, 0u, 1u);

// Device cipher: partitionable stream, out[m] = x0^x1 of block (0, m).
// Keys are compile-time constants -> key schedule folds away.
__device__ __forceinline__ unsigned rb32(unsigned k0, unsigned k1, unsigned m) {
  const unsigned ks2 = k0 ^ k1 ^ 0x1BD11BDAu;
  unsigned x0 = k0, x1 = m + k1;
#define QR(r) x0 += x1; x1 = __builtin_rotateleft32(x1, r); x1 ^= x0;
  QR(13) QR(15) QR(26) QR(6)
  x0 += k1;  x1 += ks2 + 1u;
  QR(17) QR(29) QR(16) QR(24)
  x0 += ks2; x1 += k0 + 2u;
  QR(13) QR(15) QR(26) QR(6)
  x0 += k0;  x1 += k1 + 3u;
  QR(17) QR(29) QR(16) QR(24)
  x0 += k1;  x1 += ks2 + 4u;
  QR(13) QR(15) QR(26) QR(6)
  x0 += ks2; x1 += k0 + 5u;
#undef QR
  return x0 ^ x1;
}

// ---------------------------------------------------------------------------
// normal draw: bits -> uniform[lo,1) -> sqrt(2)*erfinv (XLA/Giles poly),
// with fast hardware log (error amplification analysis: delta<=1e-6 in a
// noise value -> <=1e-3 in output, threshold 15.28).
// ---------------------------------------------------------------------------
__device__ __forceinline__ float normal_fast(unsigned bits) {
  const float lo = __uint_as_float(0xBF7FFFFFu);  // nextafter(-1,0)
  float u = __uint_as_float((bits >> 9) | 0x3F800000u) - 1.0f;  // [0,1)
  float v = fmaf(u, 2.0f, lo);                     // [lo, 1)
  float t = fmaf(-v, v, 1.0f);                     // 1 - v^2  (>= ~4.8e-7)
  float w = __builtin_amdgcn_logf(t) * -0.69314718f;  // -ln(1-v^2)
  float p;
  if (w < 5.0f) {
    float z = w - 2.5f;
    p = 2.81022636e-08f;
    p = fmaf(p, z, 3.43273939e-07f);
    p = fmaf(p, z, -3.5233877e-06f);
    p = fmaf(p, z, -4.39150654e-06f);
    p = fmaf(p, z, 0.00021858087f);
    p = fmaf(p, z, -0.00125372503f);
    p = fmaf(p, z, -0.00417768164f);
    p = fmaf(p, z, 0.246640727f);
    p = fmaf(p, z, 1.50140941f);
  } else {
    float z = __builtin_amdgcn_sqrtf(w) - 3.0f;
    p = -0.000200214257f;
    p = fmaf(p, z, 0.000100950558f);
    p = fmaf(p, z, 0.00134934322f);
    p = fmaf(p, z, -0.00367342844f);
    p = fmaf(p, z, 0.00573950773f);
    p = fmaf(p, z, -0.0076224613f);
    p = fmaf(p, z, 0.00943887047f);
    p = fmaf(p, z, 1.00167406f);
    p = fmaf(p, z, 2.83297682f);
  }
  return 1.41421356f * (p * v);
}

// ---------------------------------------------------------------------------
// Kernel 1: sem[b,c] = mean over H*W. One wave per (b,c) row.
// ---------------------------------------------------------------------------
__global__ __launch_bounds__(256) void sem_kernel(const float* __restrict__ x,
                                                  float* __restrict__ sem) {
  int row = (blockIdx.x * 256 + threadIdx.x) >> 6;
  int lane = threadIdx.x & 63;
  const float* rp = x + (size_t)row * 1024;
  float acc = 0.0f;
#pragma unroll
  for (int i = 0; i < 4; ++i) {
    float4 v = *(const float4*)(rp + i * 256 + lane * 4);
    acc += v.x + v.y + v.z + v.w;
  }
#pragma unroll
  for (int off = 32; off > 0; off >>= 1) acc += __shfl_down(acc, off, 64);
  if (lane == 0) sem[row] = acc * (1.0f / 1024.0f);
}

// ---------------------------------------------------------------------------
// Kernel 2: per-batch head -> s[b,c] = weights * topk-mask
// ---------------------------------------------------------------------------
__global__ __launch_bounds__(256) void head_kernel(
    const float* __restrict__ sem_g, const float* __restrict__ channel_embed,
    const float* __restrict__ snr_w1, const float* __restrict__ snr_b1,
    const float* __restrict__ snr_w2, const float* __restrict__ snr_b2,
    const float* __restrict__ base_w1, const float* __restrict__ base_w2,
    const float* __restrict__ sem_proj, const float* __restrict__ cond_proj,
    const float* __restrict__ out_proj, const float* __restrict__ r_w1,
    const float* __restrict__ r_b1, const float* __restrict__ r_w2,
    const float* __restrict__ r_b2, const float* __restrict__ r_w3,
    const float* __restrict__ r_b3, float* __restrict__ s_out) {
  __shared__ float sem_s[256];
  __shared__ float sv1_s[16];
  __shared__ float cond_s[32];
  __shared__ float hid_s[16], g1_s[16];
  __shared__ float r1_s[64], r2_s[64];
  __shared__ float w_s[256];
  __shared__ int k_s;
  const int b = blockIdx.x, t = threadIdx.x;

  sem_s[t] = sem_g[b * 256 + t];
  if (t < 16) {
    const float s_in = (float)(10.0 / 28.0);
    sv1_s[t] = fmaxf(0.0f, s_in * snr_w1[t] + snr_b1[t]);
  }
  __syncthreads();
  if (t < 16) {
    float a = snr_b2[t];
    for (int f = 0; f < 16; ++f) a += sv1_s[f] * snr_w2[t * 16 + f];
    cond_s[16 + t] = fmaxf(0.0f, a);
    cond_s[t] = channel_embed[2 * 16 + t];  // CH_IDX=2
  }
  __syncthreads();
  if (t < 16) {
    float a1 = 0.0f, a2 = 0.0f;
    for (int c = 0; c < 256; ++c) {
      float sc = sem_s[c];
      a1 += sc * base_w1[t * 256 + c];
      a2 += sc * sem_proj[t * 256 + c];
    }
    for (int j = 0; j < 32; ++j) a2 += cond_s[j] * cond_proj[t * 32 + j];
    hid_s[t] = fmaxf(0.0f, a1);
    g1_s[t] = fmaxf(0.0f, a2);
  } else if (t < 80) {
    int i = t - 16;
    float a = r_b1[i];
    for (int c = 0; c < 256; ++c) a += sem_s[c] * r_w1[i * 288 + c];
    for (int j = 0; j < 32; ++j) a += cond_s[j] * r_w1[i * 288 + 256 + j];
    r1_s[i] = fmaxf(0.0f, a);
  }
  __syncthreads();
  if (t < 64) {
    float a = r_b2[t];
    for (int j = 0; j < 64; ++j) a += r1_s[j] * r_w2[t * 64 + j];
    r2_s[t] = fmaxf(0.0f, a);
  }
  {
    float a1 = 0.0f, a2 = 0.0f;
    for (int i = 0; i < 16; ++i) {
      a1 += hid_s[i] * base_w2[t * 16 + i];
      a2 += g1_s[i] * out_proj[t * 16 + i];
    }
    float base = 1.0f / (1.0f + expf(-a1));
    float gate = 1.0f / (1.0f + expf(-a2));
    w_s[t] = base * gate;
  }
  __syncthreads();
  if (t == 0) {
    float a = r_b3[0];
    for (int j = 0; j < 64; ++j) a += r2_s[j] * r_w3[j];
    float raw = 1.0f / (1.0f + expf(-a));
    float dyn = 0.3f + 0.7f * raw;
    float cr = 0.15f + 0.7f * dyn;
    cr = fminf(fmaxf(cr, 0.3f), 1.0f);
    int k = (int)rintf(cr * 256.0f);
    k_s = min(max(k, 1), 256);
  }
  __syncthreads();
  {
    float wc = w_s[t];
    int cnt = 0;
    for (int j = 0; j < 256; ++j) {
      float wj = w_s[j];
      cnt += (wj > wc) || (wj == wc && j < t);
    }
    s_out[b * 256 + t] = (cnt < k_s) ? wc : 0.0f;
  }
}

// ---------------------------------------------------------------------------
// Kernel 3: channel sim + noise. One thread per float4 (= 2 complex pairs).
//   q0 = 4*tid : global float index (= flat (b,c,h,w) index)
//   m  = q0/2  : flat pair index for hr/hi/nr/ni
//   j  = q0>>5 : flat (b,c,h) row for snr_map; 8 rows per wave
// ---------------------------------------------------------------------------
__global__ __launch_bounds__(256) void sim_kernel(const float* __restrict__ x,
                                                  const float* __restrict__ s,
                                                  float* __restrict__ out) {
  const unsigned tid = blockIdx.x * 256u + threadIdx.x;   // 0 .. 4194303
  const unsigned q0 = tid * 4u;
  const unsigned lane = threadIdx.x & 63u;

  // --- snr_map std2: one all-lane cipher yields the wave's 16 needed words.
  // FORK2' (leading-2 randint layout): high = bits[j], low = bits[NROWS+j].
  const unsigned wavebase = blockIdx.x * 256u + (threadIdx.x & ~63u);
  const unsigned R0 = wavebase >> 3;                      // row of lane 0
  unsigned su = rb32(KK0.a, KK0.b,
                     ((lane & 8u) ? NROWS : 0u) + R0 + (lane & 7u));
  const unsigned g = lane >> 3;
  unsigned hb = __shfl(su, (int)g, 64);
  unsigned lb = __shfl(su, (int)(8u + g), 64);
  unsigned snr = ((hb % 29u) * 16u + (lb % 29u)) % 29u;   // 2^32 % 29 = 16
  // std2 = sqrt(2 * 10^(-snr/10)) ; 10^(-e) = exp2(-e*log2(10))
  float std2 = __builtin_amdgcn_sqrtf(
      2.0f * __builtin_amdgcn_exp2f((float)snr * -0.33219281f));

  // --- 12 independent cipher chains ---
  const unsigned m0 = tid * 2u, m1 = m0 + 1u;
  float hr0 = normal_fast(rb32(NK0.a, NK0.b, m0));
  float hr1 = normal_fast(rb32(NK0.a, NK0.b, m1));
  float hi0 = normal_fast(rb32(NK1.a, NK1.b, m0));
  float hi1 = normal_fast(rb32(NK1.a, NK1.b, m1));
  const float STD = 0.44721359f;  // sqrt(0.2) in f32
  float nr0 = STD * normal_fast(rb32(NK2.a, NK2.b, m0));
  float nr1 = STD * normal_fast(rb32(NK2.a, NK2.b, m1));
  float ni0 = STD * normal_fast(rb32(NK3.a, NK3.b, m0));
  float ni1 = STD * normal_fast(rb32(NK3.a, NK3.b, m1));
  float n20 = normal_fast(rb32(KK1.a, KK1.b, q0));
  float n21 = normal_fast(rb32(KK1.a, KK1.b, q0 + 1u));
  float n22 = normal_fast(rb32(KK1.a, KK1.b, q0 + 2u));
  float n23 = normal_fast(rb32(KK1.a, KK1.b, q0 + 3u));

  // --- signal ---
  const float4 xv = *(const float4*)(x + q0);
  const float sc = s[q0 >> 10];                           // b*256 + c
  const float xr0 = xv.x * sc, xi0 = xv.y * sc;
  const float xr1 = xv.z * sc, xi1 = xv.w * sc;

  // fading (algebraically simplified: out = x + (h* conj-mix n)/|h|^2)
  const float den0 = fmaf(hr0, hr0, hi0 * hi0);
  const float den1 = fmaf(hr1, hr1, hi1 * hi1);
  const float rc0 = __builtin_amdgcn_rcpf(den0);
  const float rc1 = __builtin_amdgcn_rcpf(den1);
  const float outr0 = fmaf(fmaf(hr0, nr0, hi0 * ni0), rc0, xr0);
  const float outi0 = fmaf(fmaf(hr0, ni0, -(hi0 * nr0)), rc0, xi0);
  const float outr1 = fmaf(fmaf(hr1, nr1, hi1 * ni1), rc1, xr1);
  const float outi1 = fmaf(fmaf(hr1, ni1, -(hi1 * nr1)), rc1, xi1);

  float4 o;
  o.x = fmaf(std2, n20, outr0);
  o.y = fmaf(std2, n21, outi0);
  o.z = fmaf(std2, n22, outr1);
  o.w = fmaf(std2, n23, outi1);
  *(float4*)(out + q0) = o;
}

// ---------------------------------------------------------------------------
extern "C" void kernel_launch(void* const* d_in, const int* in_sizes, int n_in,
                              void* d_out, int out_size, void* d_ws,
                              size_t ws_size, hipStream_t stream) {
  const float* x = (const float*)d_in[0];
  const float* channel_embed = (const float*)d_in[1];
  const float* snr_w1 = (const float*)d_in[2];
  const float* snr_b1 = (const float*)d_in[3];
  const float* snr_w2 = (const float*)d_in[4];
  const float* snr_b2 = (const float*)d_in[5];
  const float* base_w1 = (const float*)d_in[6];
  const float* base_w2 = (const float*)d_in[7];
  const float* sem_proj = (const float*)d_in[8];
  const float* cond_proj = (const float*)d_in[9];
  const float* out_proj = (const float*)d_in[10];
  const float* r_w1 = (const float*)d_in[11];
  const float* r_b1 = (const float*)d_in[12];
  const float* r_w2 = (const float*)d_in[13];
  const float* r_b2 = (const float*)d_in[14];
  const float* r_w3 = (const float*)d_in[15];
  const float* r_b3 = (const float*)d_in[16];

  float* sem = (float*)d_ws;              // 16384 floats
  float* s = sem + NB * NC;               // 16384 floats

  sem_kernel<<<NB * NC / 4, 256, 0, stream>>>(x, sem);
  head_kernel<<<NB, 256, 0, stream>>>(sem, channel_embed, snr_w1, snr_b1,
                                      snr_w2, snr_b2, base_w1, base_w2,
                                      sem_proj, cond_proj, out_proj, r_w1,
                                      r_b1, r_w2, r_b2, r_w3, r_b3, s);
  sim_kernel<<<NB * NPAIR / 2 / 256, 256, 0, stream>>>(x, s, (float*)d_out);
}

// Round 3
// 134.346 us; speedup vs baseline: 1.8973x; 1.0315x over previous
//
#include <hip/hip_runtime.h>

#define NB 64
#define NC 256
#define NF 262144          // C*H*W per batch
#define NPAIR 131072       // complex pairs per batch
#define NROWS 524288       // B*C*H  (snr_map rows)

// ---------------------------------------------------------------------------
// Threefry-2x32 (JAX), 20 rounds.
// ---------------------------------------------------------------------------
struct U2 { unsigned a, b; };

__host__ __device__ constexpr unsigned rotl32(unsigned x, int d) {
  return (x << d) | (x >> (32 - d));
}

__host__ __device__ constexpr U2 tf2x32(unsigned k0, unsigned k1,
                                        unsigned x0, unsigned x1) {
  const unsigned ks0 = k0, ks1 = k1, ks2 = k0 ^ k1 ^ 0x1BD11BDAu;
  x0 += ks0; x1 += ks1;
  x0 += x1; x1 = rotl32(x1, 13); x1 ^= x0;
  x0 += x1; x1 = rotl32(x1, 15); x1 ^= x0;
  x0 += x1; x1 = rotl32(x1, 26); x1 ^= x0;
  x0 += x1; x1 = rotl32(x1, 6);  x1 ^= x0;
  x0 += ks1; x1 += ks2 + 1u;
  x0 += x1; x1 = rotl32(x1, 17); x1 ^= x0;
  x0 += x1; x1 = rotl32(x1, 29); x1 ^= x0;
  x0 += x1; x1 = rotl32(x1, 16); x1 ^= x0;
  x0 += x1; x1 = rotl32(x1, 24); x1 ^= x0;
  x0 += ks2; x1 += ks0 + 2u;
  x0 += x1; x1 = rotl32(x1, 13); x1 ^= x0;
  x0 += x1; x1 = rotl32(x1, 15); x1 ^= x0;
  x0 += x1; x1 = rotl32(x1, 26); x1 ^= x0;
  x0 += x1; x1 = rotl32(x1, 6);  x1 ^= x0;
  x0 += ks0; x1 += ks1 + 3u;
  x0 += x1; x1 = rotl32(x1, 17); x1 ^= x0;
  x0 += x1; x1 = rotl32(x1, 29); x1 ^= x0;
  x0 += x1; x1 = rotl32(x1, 16); x1 ^= x0;
  x0 += x1; x1 = rotl32(x1, 24); x1 ^= x0;
  x0 += ks1; x1 += ks2 + 4u;
  x0 += x1; x1 = rotl32(x1, 13); x1 ^= x0;
  x0 += x1; x1 = rotl32(x1, 15); x1 ^= x0;
  x0 += x1; x1 = rotl32(x1, 26); x1 ^= x0;
  x0 += x1; x1 = rotl32(x1, 6);  x1 ^= x0;
  x0 += ks2; x1 += ks0 + 5u;
  return U2{x0, x1};
}

// nk = split(key(42), 5); key(42) = (0, 42)
constexpr U2 NK0 = tf2x32(0u, 42u, 0u, 0u);
constexpr U2 NK1 = tf2x32(0u, 42u, 0u, 1u);
constexpr U2 NK2 = tf2x32(0u, 42u, 0u, 2u);
constexpr U2 NK3 = tf2x32(0u, 42u, 0u, 3u);
constexpr U2 NK4 = tf2x32(0u, 42u, 0u, 4u);
// kk = split(nk[4], 2)
constexpr U2 KK0 = tf2x32(NK4.a, NK4.b, 0u, 0u);
constexpr U2 KK1 = tf2x32(NK4.a, NK4.b, 0u, 1u);

// Device cipher: partitionable stream, out[m] = x0^x1 of block (0, m).
__device__ __forceinline__ unsigned rb32(unsigned k0, unsigned k1, unsigned m) {
  const unsigned ks2 = k0 ^ k1 ^ 0x1BD11BDAu;
  unsigned x0 = k0, x1 = m + k1;
#define QR(r) x0 += x1; x1 = __builtin_rotateleft32(x1, r); x1 ^= x0;
  QR(13) QR(15) QR(26) QR(6)
  x0 += k1;  x1 += ks2 + 1u;
  QR(17) QR(29) QR(16) QR(24)
  x0 += ks2; x1 += k0 + 2u;
  QR(13) QR(15) QR(26) QR(6)
  x0 += k0;  x1 += k1 + 3u;
  QR(17) QR(29) QR(16) QR(24)
  x0 += k1;  x1 += ks2 + 4u;
  QR(13) QR(15) QR(26) QR(6)
  x0 += ks2; x1 += k0 + 5u;
#undef QR
  return x0 ^ x1;
}

// ---------------------------------------------------------------------------
// normal draw: bits -> uniform[lo,1) -> sqrt(2)*erfinv (XLA/Giles poly),
// hw log2 (error amplification bounded: delta<=1e-6 -> <=1e-3 in output).
// ---------------------------------------------------------------------------
__device__ __forceinline__ float normal_fast(unsigned bits) {
  const float lo = __uint_as_float(0xBF7FFFFFu);  // nextafter(-1,0)
  float u = __uint_as_float((bits >> 9) | 0x3F800000u) - 1.0f;  // [0,1)
  float v = fmaf(u, 2.0f, lo);                     // [lo, 1)
  float t = fmaf(-v, v, 1.0f);                     // 1 - v^2
  float w = __builtin_amdgcn_logf(t) * -0.69314718f;  // -ln(1-v^2)
  float p;
  if (w < 5.0f) {
    float z = w - 2.5f;
    p = 2.81022636e-08f;
    p = fmaf(p, z, 3.43273939e-07f);
    p = fmaf(p, z, -3.5233877e-06f);
    p = fmaf(p, z, -4.39150654e-06f);
    p = fmaf(p, z, 0.00021858087f);
    p = fmaf(p, z, -0.00125372503f);
    p = fmaf(p, z, -0.00417768164f);
    p = fmaf(p, z, 0.246640727f);
    p = fmaf(p, z, 1.50140941f);
  } else {
    float z = __builtin_amdgcn_sqrtf(w) - 3.0f;
    p = -0.000200214257f;
    p = fmaf(p, z, 0.000100950558f);
    p = fmaf(p, z, 0.00134934322f);
    p = fmaf(p, z, -0.00367342844f);
    p = fmaf(p, z, 0.00573950773f);
    p = fmaf(p, z, -0.0076224613f);
    p = fmaf(p, z, 0.00943887047f);
    p = fmaf(p, z, 1.00167406f);
    p = fmaf(p, z, 2.83297682f);
  }
  return 1.41421356f * (p * v);
}

// ---------------------------------------------------------------------------
// Kernel 0: std2[j] for each (b,c,h) row from randint(kk0, (b,c,h,1), 0, 29).
// Leading-2 bits layout: high = bits[j], low = bits[NROWS + j].
// ---------------------------------------------------------------------------
__global__ __launch_bounds__(256) void snr_kernel(float* __restrict__ std2) {
  const unsigned j = blockIdx.x * 256u + threadIdx.x;  // 0..524287
  unsigned hb = rb32(KK0.a, KK0.b, j);
  unsigned lb = rb32(KK0.a, KK0.b, NROWS + j);
  unsigned snr = ((hb % 29u) * 16u + (lb % 29u)) % 29u;  // 2^32 % 29 = 16
  std2[j] = __builtin_amdgcn_sqrtf(
      2.0f * __builtin_amdgcn_exp2f((float)snr * -0.33219281f));
}

// ---------------------------------------------------------------------------
// Kernel 1: sem[b,c] = mean over H*W. One wave per (b,c) row.
// ---------------------------------------------------------------------------
__global__ __launch_bounds__(256) void sem_kernel(const float* __restrict__ x,
                                                  float* __restrict__ sem) {
  int row = (blockIdx.x * 256 + threadIdx.x) >> 6;
  int lane = threadIdx.x & 63;
  const float* rp = x + (size_t)row * 1024;
  float acc = 0.0f;
#pragma unroll
  for (int i = 0; i < 4; ++i) {
    float4 v = *(const float4*)(rp + i * 256 + lane * 4);
    acc += v.x + v.y + v.z + v.w;
  }
#pragma unroll
  for (int off = 32; off > 0; off >>= 1) acc += __shfl_down(acc, off, 64);
  if (lane == 0) sem[row] = acc * (1.0f / 1024.0f);
}

// ---------------------------------------------------------------------------
// Kernel 2: per-batch head -> s[b,c] = weights * topk-mask
// ---------------------------------------------------------------------------
__global__ __launch_bounds__(256) void head_kernel(
    const float* __restrict__ sem_g, const float* __restrict__ channel_embed,
    const float* __restrict__ snr_w1, const float* __restrict__ snr_b1,
    const float* __restrict__ snr_w2, const float* __restrict__ snr_b2,
    const float* __restrict__ base_w1, const float* __restrict__ base_w2,
    const float* __restrict__ sem_proj, const float* __restrict__ cond_proj,
    const float* __restrict__ out_proj, const float* __restrict__ r_w1,
    const float* __restrict__ r_b1, const float* __restrict__ r_w2,
    const float* __restrict__ r_b2, const float* __restrict__ r_w3,
    const float* __restrict__ r_b3, float* __restrict__ s_out) {
  __shared__ float sem_s[256];
  __shared__ float sv1_s[16];
  __shared__ float cond_s[32];
  __shared__ float hid_s[16], g1_s[16];
  __shared__ float r1_s[64], r2_s[64];
  __shared__ float w_s[256];
  __shared__ int k_s;
  const int b = blockIdx.x, t = threadIdx.x;

  sem_s[t] = sem_g[b * 256 + t];
  if (t < 16) {
    const float s_in = (float)(10.0 / 28.0);
    sv1_s[t] = fmaxf(0.0f, s_in * snr_w1[t] + snr_b1[t]);
  }
  __syncthreads();
  if (t < 16) {
    float a = snr_b2[t];
    for (int f = 0; f < 16; ++f) a += sv1_s[f] * snr_w2[t * 16 + f];
    cond_s[16 + t] = fmaxf(0.0f, a);
    cond_s[t] = channel_embed[2 * 16 + t];  // CH_IDX=2
  }
  __syncthreads();
  if (t < 16) {
    float a1 = 0.0f, a2 = 0.0f;
    for (int c = 0; c < 256; ++c) {
      float sc = sem_s[c];
      a1 += sc * base_w1[t * 256 + c];
      a2 += sc * sem_proj[t * 256 + c];
    }
    for (int j = 0; j < 32; ++j) a2 += cond_s[j] * cond_proj[t * 32 + j];
    hid_s[t] = fmaxf(0.0f, a1);
    g1_s[t] = fmaxf(0.0f, a2);
  } else if (t < 80) {
    int i = t - 16;
    float a = r_b1[i];
    for (int c = 0; c < 256; ++c) a += sem_s[c] * r_w1[i * 288 + c];
    for (int j = 0; j < 32; ++j) a += cond_s[j] * r_w1[i * 288 + 256 + j];
    r1_s[i] = fmaxf(0.0f, a);
  }
  __syncthreads();
  if (t < 64) {
    float a = r_b2[t];
    for (int j = 0; j < 64; ++j) a += r1_s[j] * r_w2[t * 64 + j];
    r2_s[t] = fmaxf(0.0f, a);
  }
  {
    float a1 = 0.0f, a2 = 0.0f;
    for (int i = 0; i < 16; ++i) {
      a1 += hid_s[i] * base_w2[t * 16 + i];
      a2 += g1_s[i] * out_proj[t * 16 + i];
    }
    float base = 1.0f / (1.0f + expf(-a1));
    float gate = 1.0f / (1.0f + expf(-a2));
    w_s[t] = base * gate;
  }
  __syncthreads();
  if (t == 0) {
    float a = r_b3[0];
    for (int j = 0; j < 64; ++j) a += r2_s[j] * r_w3[j];
    float raw = 1.0f / (1.0f + expf(-a));
    float dyn = 0.3f + 0.7f * raw;
    float cr = 0.15f + 0.7f * dyn;
    cr = fminf(fmaxf(cr, 0.3f), 1.0f);
    int k = (int)rintf(cr * 256.0f);
    k_s = min(max(k, 1), 256);
  }
  __syncthreads();
  {
    float wc = w_s[t];
    int cnt = 0;
    for (int j = 0; j < 256; ++j) {
      float wj = w_s[j];
      cnt += (wj > wc) || (wj == wc && j < t);
    }
    s_out[b * 256 + t] = (cnt < k_s) ? wc : 0.0f;
  }
}

// ---------------------------------------------------------------------------
// Kernel 3: channel sim + noise. One thread per 8 floats (= 4 complex pairs).
//   q0 = 8*tid : global flat float index; all 8 floats share channel & row.
// ---------------------------------------------------------------------------
__global__ __launch_bounds__(256) void sim_kernel(const float* __restrict__ x,
                                                  const float* __restrict__ s,
                                                  const float* __restrict__ std2v,
                                                  float* __restrict__ out) {
  const unsigned tid = blockIdx.x * 256u + threadIdx.x;   // 0 .. 2097151
  const unsigned q0 = tid * 8u;

  // loads issued early; consumed at the end (latency hidden under ciphers)
  const float4 xa = *(const float4*)(x + q0);
  const float4 xb = *(const float4*)(x + q0 + 4);
  const float sc = s[q0 >> 10];       // per-channel weight (block-broadcast)
  const float std2 = std2v[q0 >> 5];  // per-row noise std (4-thread broadcast)

  // --- 24 independent cipher chains: 16 for h/n (pairs m0..m0+3), 8 for n2.
  const unsigned m0 = tid * 4u;
  float hr[4], hi[4], nr[4], ni[4], n2[8];
  const float STD = 0.44721359f;  // sqrt(0.2)
#pragma unroll
  for (int i = 0; i < 4; ++i) hr[i] = normal_fast(rb32(NK0.a, NK0.b, m0 + i));
#pragma unroll
  for (int i = 0; i < 4; ++i) hi[i] = normal_fast(rb32(NK1.a, NK1.b, m0 + i));
#pragma unroll
  for (int i = 0; i < 4; ++i)
    nr[i] = STD * normal_fast(rb32(NK2.a, NK2.b, m0 + i));
#pragma unroll
  for (int i = 0; i < 4; ++i)
    ni[i] = STD * normal_fast(rb32(NK3.a, NK3.b, m0 + i));
#pragma unroll
  for (int i = 0; i < 8; ++i) n2[i] = normal_fast(rb32(KK1.a, KK1.b, q0 + i));

  // --- fading: out = x*sc + (h* . n)/|h|^2 + std2*n2 ---
  float xs[8] = {xa.x * sc, xa.y * sc, xa.z * sc, xa.w * sc,
                 xb.x * sc, xb.y * sc, xb.z * sc, xb.w * sc};
  float o[8];
#pragma unroll
  for (int i = 0; i < 4; ++i) {
    const float den = fmaf(hr[i], hr[i], hi[i] * hi[i]);
    const float rc = __builtin_amdgcn_rcpf(den);
    o[2 * i] = fmaf(fmaf(hr[i], nr[i], hi[i] * ni[i]), rc, xs[2 * i]);
    o[2 * i + 1] = fmaf(fmaf(hr[i], ni[i], -(hi[i] * nr[i])), rc, xs[2 * i + 1]);
  }
  float4 oa, ob;
  oa.x = fmaf(std2, n2[0], o[0]);
  oa.y = fmaf(std2, n2[1], o[1]);
  oa.z = fmaf(std2, n2[2], o[2]);
  oa.w = fmaf(std2, n2[3], o[3]);
  ob.x = fmaf(std2, n2[4], o[4]);
  ob.y = fmaf(std2, n2[5], o[5]);
  ob.z = fmaf(std2, n2[6], o[6]);
  ob.w = fmaf(std2, n2[7], o[7]);
  *(float4*)(out + q0) = oa;
  *(float4*)(out + q0 + 4) = ob;
}

// ---------------------------------------------------------------------------
extern "C" void kernel_launch(void* const* d_in, const int* in_sizes, int n_in,
                              void* d_out, int out_size, void* d_ws,
                              size_t ws_size, hipStream_t stream) {
  const float* x = (const float*)d_in[0];
  const float* channel_embed = (const float*)d_in[1];
  const float* snr_w1 = (const float*)d_in[2];
  const float* snr_b1 = (const float*)d_in[3];
  const float* snr_w2 = (const float*)d_in[4];
  const float* snr_b2 = (const float*)d_in[5];
  const float* base_w1 = (const float*)d_in[6];
  const float* base_w2 = (const float*)d_in[7];
  const float* sem_proj = (const float*)d_in[8];
  const float* cond_proj = (const float*)d_in[9];
  const float* out_proj = (const float*)d_in[10];
  const float* r_w1 = (const float*)d_in[11];
  const float* r_b1 = (const float*)d_in[12];
  const float* r_w2 = (const float*)d_in[13];
  const float* r_b2 = (const float*)d_in[14];
  const float* r_w3 = (const float*)d_in[15];
  const float* r_b3 = (const float*)d_in[16];

  float* std2 = (float*)d_ws;             // 524288 floats (2 MB)
  float* sem = std2 + NROWS;              // 16384 floats
  float* s = sem + NB * NC;               // 16384 floats

  sem_kernel<<<NB * NC / 4, 256, 0, stream>>>(x, sem);
  snr_kernel<<<NROWS / 256, 256, 0, stream>>>(std2);
  head_kernel<<<NB, 256, 0, stream>>>(sem, channel_embed, snr_w1, snr_b1,
                                      snr_w2, snr_b2, base_w1, base_w2,
                                      sem_proj, cond_proj, out_proj, r_w1,
                                      r_b1, r_w2, r_b2, r_w3, r_b3, s);
  sim_kernel<<<NB * NF / 8 / 256, 256, 0, stream>>>(x, s, std2, (float*)d_out);
}